// Round 8
// baseline (336.644 us; speedup 1.0000x reference)
//
#include <hip/hip_runtime.h>
#include <hip/hip_bf16.h>

// Problem constants
#define HDIM   2880
#define NH     64
#define NKV    8
#define DHEAD  64
#define GQ     (NH / NKV)     // 8
#define WIN    128
#define NTOK   1024
#define QKV_N  ((NH + 2 * NKV) * DHEAD)   // 5120
#define QCOLS  (NH * DHEAD)               // 4096
#define KOFF   QCOLS                      // 4096
#define VOFF   (QCOLS + NKV * DHEAD)      // 4608
#define WO_PAD 3072                       // 2880 padded to 24*128 (8-divisible tiles)
#define SK1    3                          // split-K qkv gemm (2880 = 3*960)
#define SK2    4                          // split-K out gemm (4096 = 4*1024)

typedef __attribute__((ext_vector_type(8))) short short8;
typedef __attribute__((ext_vector_type(4))) float floatx4;

// Static device scratch (zero-init at module load; WoT pad rows stay zero).
__device__ unsigned short g_Xb   [(size_t)NTOK  * HDIM];          //  5.9 MB
__device__ unsigned short g_qkvb [(size_t)NTOK  * QKV_N];         // 10.5 MB bf16 qkv (post-rope)
__device__ unsigned short g_attn [(size_t)NTOK  * QCOLS];         //  8.4 MB
__device__ unsigned short g_WqkvT[(size_t)QKV_N * HDIM];          // 29.5 MB
__device__ unsigned short g_WoT  [(size_t)WO_PAD * QCOLS];        // 25.2 MB (padded)
__device__ float          g_part1[(size_t)SK1 * NTOK * QKV_N];    // 62.9 MB f32 partials
__device__ float          g_part2[(size_t)SK2 * NTOK * WO_PAD];   // 50.3 MB f32 partials

__device__ __forceinline__ unsigned short f2b(float f) {
    __hip_bfloat16 h = __float2bfloat16(f);
    return *reinterpret_cast<unsigned short*>(&h);
}

__device__ __forceinline__ void gload_lds16(const unsigned short* g, unsigned short* l) {
    __builtin_amdgcn_global_load_lds(
        (const __attribute__((address_space(1))) unsigned int*)g,
        (__attribute__((address_space(3))) unsigned int*)l, 16, 0, 0);
}

// ---------------------------------------------------------------------------
// Fused prep: Wqkv transpose+cvt | Wo transpose+cvt | X cvt, one launch.
// Transpose blocks: in (K x N f32) tile (bk,bn) -> out (N x K bf16).
// ---------------------------------------------------------------------------
#define T1_BLKS (45 * 80)   // Wqkv: K=2880 (45), N=5120 (80)
#define T2_BLKS (64 * 45)   // Wo:   K=4096 (64), N=2880 (45)
#define CV_BLKS 2880        // X: 1024*2880/4/256

__global__ __launch_bounds__(256) void prep(
        const float* __restrict__ X, const float* __restrict__ Wqkv,
        const float* __restrict__ Wo, unsigned short* __restrict__ Xb,
        unsigned short* __restrict__ WqkvT, unsigned short* __restrict__ WoT) {
    __shared__ __align__(16) unsigned short T[64 * 72];
    int b = blockIdx.x, t = threadIdx.x;
    const float* in;
    unsigned short* out;
    int K, N, bk, bn;
    if (b < T1_BLKS) {
        in = Wqkv; out = WqkvT; K = HDIM; N = QKV_N;
        bk = b % 45; bn = b / 45;
    } else if (b < T1_BLKS + T2_BLKS) {
        int b2 = b - T1_BLKS;
        in = Wo; out = WoT; K = QCOLS; N = HDIM;
        bk = b2 % 64; bn = b2 / 64;
    } else {
        int id = (b - T1_BLKS - T2_BLKS) * 256 + t;
        float4 v = *(const float4*)(X + (size_t)id * 4);
        ushort4 o;
        o.x = f2b(v.x); o.y = f2b(v.y); o.z = f2b(v.z); o.w = f2b(v.w);
        *(ushort4*)(Xb + (size_t)id * 4) = o;
        return;
    }
    #pragma unroll
    for (int i = 0; i < 4; ++i) {
        int c = i * 256 + t;          // float4 slots
        int r = c >> 4, cc = (c & 15) * 4;
        float4 v = *(const float4*)(in + (size_t)(bk * 64 + r) * N + bn * 64 + cc);
        T[r * 72 + cc + 0] = f2b(v.x);
        T[r * 72 + cc + 1] = f2b(v.y);
        T[r * 72 + cc + 2] = f2b(v.z);
        T[r * 72 + cc + 3] = f2b(v.w);
    }
    __syncthreads();
    #pragma unroll
    for (int i = 0; i < 2; ++i) {
        int c = i * 256 + t;
        int rn = c >> 3, kc = (c & 7) * 8;
        int4 vv;
        unsigned short* tp = (unsigned short*)&vv;
        #pragma unroll
        for (int j = 0; j < 8; ++j) tp[j] = T[(kc + j) * 72 + rn];
        *(int4*)(out + (size_t)(bn * 64 + rn) * K + bk * 64 + kc) = vv;
    }
}

// ---------------------------------------------------------------------------
// Split-K GEMM with XCD-aware 1D grid: all (bm,z) for a bn land on the same
// XCD (assumes round-robin wg->XCD: xcd = lin % 8) so the B chunk stays L2-
// resident. grid = 8 * (BN/8) * 8 * sk ; BM fixed = 8 (M=1024).
// 128x128 tile, BK=64, 4 waves (2x2), 4x4 MFMA tiles/wave, global_load_lds.
// ---------------------------------------------------------------------------
__global__ __launch_bounds__(256) void gemm_sk(
        const unsigned short* __restrict__ A, const unsigned short* __restrict__ Bt,
        float* __restrict__ P, int K, int chunk, int ldc, size_t plane, int sk) {
    int sk8 = sk << 3;
    int xcd = blockIdx.x & 7;
    int idx = blockIdx.x >> 3;
    int grp = idx / sk8;
    int rem = idx - grp * sk8;
    int bn = xcd + (grp << 3);
    int bm = rem & 7;
    int z  = rem >> 3;

    int t = threadIdx.x, lane = t & 63, wid = t >> 6;
    int quad = lane >> 4, ml = lane & 15;
    int wm = wid >> 1, wn = wid & 1;
    __shared__ __align__(16) unsigned short As[128 * 64];
    __shared__ __align__(16) unsigned short Bs[128 * 64];
    floatx4 acc[4][4];
    #pragma unroll
    for (int i = 0; i < 4; ++i)
        #pragma unroll
        for (int j = 0; j < 4; ++j) acc[i][j] = (floatx4){0.f, 0.f, 0.f, 0.f};

    int srow = lane >> 3;            // 0..7 within an 8-row group
    int scol = (lane & 7) * 8;       // 0..56
    int base = z * chunk;
    const unsigned short* Ab = A  + (size_t)(bm * 128) * K + base;
    const unsigned short* Bb = Bt + (size_t)(bn * 128) * K + base;

    for (int k0 = 0; k0 < chunk; k0 += 64) {
        #pragma unroll
        for (int j = 0; j < 4; ++j) {
            int grp8 = wid * 4 + j;              // 0..15: 8-row group
            int r = grp8 * 8 + srow;             // 0..127
            gload_lds16(Ab + (size_t)r * K + k0 + scol, &As[grp8 * 512]);
            gload_lds16(Bb + (size_t)r * K + k0 + scol, &Bs[grp8 * 512]);
        }
        __syncthreads();
        #pragma unroll
        for (int kk = 0; kk < 64; kk += 32) {
            short8 af[4], bf[4];
            #pragma unroll
            for (int mt = 0; mt < 4; ++mt)
                af[mt] = *(const short8*)&As[(wm * 64 + mt * 16 + ml) * 64 + kk + quad * 8];
            #pragma unroll
            for (int nt = 0; nt < 4; ++nt)
                bf[nt] = *(const short8*)&Bs[(wn * 64 + nt * 16 + ml) * 64 + kk + quad * 8];
            #pragma unroll
            for (int mt = 0; mt < 4; ++mt)
                #pragma unroll
                for (int nt = 0; nt < 4; ++nt)
                    acc[mt][nt] = __builtin_amdgcn_mfma_f32_16x16x32_bf16(af[mt], bf[nt], acc[mt][nt], 0, 0, 0);
        }
        __syncthreads();
    }
    float* Cp = P + z * plane;
    #pragma unroll
    for (int mt = 0; mt < 4; ++mt)
        #pragma unroll
        for (int nt = 0; nt < 4; ++nt)
            #pragma unroll
            for (int r = 0; r < 4; ++r) {
                int row = bm * 128 + wm * 64 + mt * 16 + quad * 4 + r;
                int col = bn * 128 + wn * 64 + nt * 16 + ml;
                Cp[(size_t)row * ldc + col] = acc[mt][nt][r];
            }
}

// ---------------------------------------------------------------------------
// Reduce SK1 qkv partials + RoPE (f32) -> bf16 qkv. positions == row index.
// ---------------------------------------------------------------------------
#define QK_UNITS (NTOK * 72 * 8)   // 589824
#define V_UNITS  (NTOK * 128)      // 131072
__global__ __launch_bounds__(256) void reduce_rope(
        const float* __restrict__ P, unsigned short* __restrict__ qkvb) {
    int id = blockIdx.x * 256 + threadIdx.x;
    const size_t plane = (size_t)NTOK * QKV_N;
    if (id < QK_UNITS) {
        int n = id / 576;
        int rem = id - n * 576;
        int hh = rem >> 3, q8 = rem & 7;
        int c0 = (hh < NH) ? hh * 64 : KOFF + (hh - NH) * 64;
        size_t i1 = (size_t)n * QKV_N + c0 + q8 * 4;
        float4 a0 = *(const float4*)(P + i1);
        float4 a1 = *(const float4*)(P + plane + i1);
        float4 a2 = *(const float4*)(P + 2 * plane + i1);
        float4 b0 = *(const float4*)(P + i1 + 32);
        float4 b1 = *(const float4*)(P + plane + i1 + 32);
        float4 b2 = *(const float4*)(P + 2 * plane + i1 + 32);
        float x1[4] = {a0.x + a1.x + a2.x, a0.y + a1.y + a2.y,
                       a0.z + a1.z + a2.z, a0.w + a1.w + a2.w};
        float x2[4] = {b0.x + b1.x + b2.x, b0.y + b1.y + b2.y,
                       b0.z + b1.z + b2.z, b0.w + b1.w + b2.w};
        union { ushort4 v; unsigned short u[4]; } o1, o2;
        #pragma unroll
        for (int j = 0; j < 4; ++j) {
            int d = q8 * 4 + j;
            float inv = expf(-(float)d * 0.3724497053f);   // theta^(-d/32)
            float ang = (float)n * inv;
            float s, c;
            sincosf(ang, &s, &c);
            o1.u[j] = f2b(x1[j] * c - x2[j] * s);
            o2.u[j] = f2b(x2[j] * c + x1[j] * s);
        }
        *(ushort4*)(qkvb + i1) = o1.v;
        *(ushort4*)(qkvb + i1 + 32) = o2.v;
    } else if (id < QK_UNITS + V_UNITS) {
        int vid = id - QK_UNITS;
        int n = vid >> 7, s8 = vid & 127;
        size_t i1 = (size_t)n * QKV_N + VOFF + s8 * 4;
        float4 a0 = *(const float4*)(P + i1);
        float4 a1 = *(const float4*)(P + plane + i1);
        float4 a2 = *(const float4*)(P + 2 * plane + i1);
        union { ushort4 v; unsigned short u[4]; } o;
        o.u[0] = f2b(a0.x + a1.x + a2.x);
        o.u[1] = f2b(a0.y + a1.y + a2.y);
        o.u[2] = f2b(a0.z + a1.z + a2.z);
        o.u[3] = f2b(a0.w + a1.w + a2.w);
        *(ushort4*)(qkvb + i1) = o.v;
    }
}

// ---------------------------------------------------------------------------
// Reduce SK2 out-proj partials (ldc WO_PAD) -> f32 out (ld HDIM).
// ---------------------------------------------------------------------------
__global__ __launch_bounds__(256) void reduce_out(
        const float* __restrict__ P, float* __restrict__ out) {
    int id = blockIdx.x * 256 + threadIdx.x;
    if (id >= NTOK * (HDIM / 4)) return;
    int n = id / (HDIM / 4);
    int c = (id - n * (HDIM / 4)) * 4;
    const size_t plane = (size_t)NTOK * WO_PAD;
    size_t i = (size_t)n * WO_PAD + c;
    float4 a0 = *(const float4*)(P + i);
    float4 a1 = *(const float4*)(P + plane + i);
    float4 a2 = *(const float4*)(P + 2 * plane + i);
    float4 a3 = *(const float4*)(P + 3 * plane + i);
    float4 s;
    s.x = a0.x + a1.x + a2.x + a3.x;
    s.y = a0.y + a1.y + a2.y + a3.y;
    s.z = a0.z + a1.z + a2.z + a3.z;
    s.w = a0.w + a1.w + a2.w + a3.w;
    *(float4*)(out + (size_t)n * HDIM + c) = s;
}

// ---------------------------------------------------------------------------
// MFMA flash-style sliding-window attention with sinks, bf16 in/out.
// Block = (16-token Q-tile, kv-head) -> grid 64x8 = 512 blocks (2/CU).
// Vt staging: lane->(w fast) so scatter writes hit 64 distinct w ->
// 2 lanes/bank (free) instead of the old 16-way conflict.
// ---------------------------------------------------------------------------
#define TQ     16
#define WROWS  160
#define KS_LD  72
#define VT_LD  168
#define PS_LD  168

__global__ __launch_bounds__(256) void attn_mfma(
        const unsigned short* __restrict__ qkvb,
        const float* __restrict__ sinks,
        unsigned short* __restrict__ aout) {
    int t0 = blockIdx.x * TQ, kh = blockIdx.y;
    int t = threadIdx.x, lane = t & 63, wid = t >> 6;
    int quad = lane >> 4, ml = lane & 15;
    int wavebase = wid * 32;

    __shared__ __align__(16) unsigned short Ks[WROWS * KS_LD];    // 22.5 KB
    __shared__ __align__(16) unsigned short Vt[DHEAD * VT_LD];    // 21   KB
    __shared__ __align__(16) unsigned short Ps[4 * 16 * PS_LD];   // 21   KB
    unsigned short* Psw = &Ps[wid * 16 * PS_LD];

    // ---- stage K row-major (coalesced int4)
    #pragma unroll
    for (int i = 0; i < 5; ++i) {
        int c = i * 256 + t;              // 0..1279 int4 slots
        int w = c >> 3, d8 = (c & 7) * 8;
        int r = t0 - 127 + w;
        r = min(max(r, 0), NTOK - 1);
        *(int4*)&Ks[w * KS_LD + d8] =
            *(const int4*)(qkvb + (size_t)r * QKV_N + KOFF + kh * DHEAD + d8);
    }
    // ---- stage V transposed: w varies across lanes -> conflict-free scatter
    #pragma unroll
    for (int i = 0; i < 5; ++i) {
        int c = i * 256 + t;              // 0..1279
        int w = c % 160, d8 = (c / 160) * 8;
        int r = t0 - 127 + w;
        r = min(max(r, 0), NTOK - 1);
        int4 vv = *(const int4*)(qkvb + (size_t)r * QKV_N + VOFF + kh * DHEAD + d8);
        const unsigned short* vp = (const unsigned short*)&vv;
        #pragma unroll
        for (int j = 0; j < 8; ++j) Vt[(d8 + j) * VT_LD + w] = vp[j];
    }
    __syncthreads();

    // ---- Q A-fragments straight from global bf16
    short8 qf[2][2];
    #pragma unroll
    for (int mt = 0; mt < 2; ++mt) {
        int m = wavebase + mt * 16 + ml;
        int tl = m & 15, g = m >> 4;
        const unsigned short* qp = qkvb + (size_t)(t0 + tl) * QKV_N + (kh * GQ + g) * DHEAD;
        #pragma unroll
        for (int kk = 0; kk < 2; ++kk)
            qf[mt][kk] = *(const short8*)(qp + kk * 32 + quad * 8);
    }

    // ---- S = Q K^T  (this wave: 2 m-tiles x 10 n-tiles)
    floatx4 S[2][10];
    #pragma unroll
    for (int mt = 0; mt < 2; ++mt)
        #pragma unroll
        for (int nt = 0; nt < 10; ++nt) S[mt][nt] = (floatx4){0.f, 0.f, 0.f, 0.f};
    #pragma unroll
    for (int kk = 0; kk < 2; ++kk) {
        #pragma unroll
        for (int nt = 0; nt < 10; ++nt) {
            short8 kb = *(const short8*)&Ks[(nt * 16 + ml) * KS_LD + kk * 32 + quad * 8];
            #pragma unroll
            for (int mt = 0; mt < 2; ++mt)
                S[mt][nt] = __builtin_amdgcn_mfma_f32_16x16x32_bf16(qf[mt][kk], kb, S[mt][nt], 0, 0, 0);
        }
    }

    // ---- band mask + scale   (valid: w>=tl, w<=tl+127, w>=127-t0)
    int wmin0 = 127 - t0;
    #pragma unroll
    for (int mt = 0; mt < 2; ++mt) {
        #pragma unroll
        for (int r = 0; r < 4; ++r) {
            int tl = (wavebase + mt * 16 + quad * 4 + r) & 15;
            int wlo = tl > wmin0 ? tl : wmin0;
            int whi = tl + 127;
            #pragma unroll
            for (int nt = 0; nt < 10; ++nt) {
                int w = nt * 16 + ml;
                float s = S[mt][nt][r] * 0.125f;
                S[mt][nt][r] = (w >= wlo && w <= whi) ? s : -INFINITY;
            }
        }
    }

    // ---- softmax with sink (rows spread over 16 lanes of the quad)
    #pragma unroll
    for (int mt = 0; mt < 2; ++mt) {
        int g = (wavebase + mt * 16) >> 4;
        float sk = sinks[kh * GQ + g];
        #pragma unroll
        for (int r = 0; r < 4; ++r) {
            float rm = -INFINITY;
            #pragma unroll
            for (int nt = 0; nt < 10; ++nt) rm = fmaxf(rm, S[mt][nt][r]);
            #pragma unroll
            for (int off = 1; off < 16; off <<= 1) rm = fmaxf(rm, __shfl_xor(rm, off));
            rm = fmaxf(rm, sk);
            float sum = 0.f;
            #pragma unroll
            for (int nt = 0; nt < 10; ++nt) {
                float p = __expf(S[mt][nt][r] - rm);   // exp(-inf)=0 masks
                S[mt][nt][r] = p;
                sum += p;
            }
            #pragma unroll
            for (int off = 1; off < 16; off <<= 1) sum += __shfl_xor(sum, off);
            float inv = 1.f / (sum + __expf(sk - rm));
            #pragma unroll
            for (int nt = 0; nt < 10; ++nt) S[mt][nt][r] *= inv;
        }
    }

    // ---- PV one m-tile at a time through per-wave Ps (wave DS ops in-order)
    #pragma unroll
    for (int mt = 0; mt < 2; ++mt) {
        #pragma unroll
        for (int r = 0; r < 4; ++r) {
            int lr = quad * 4 + r;
            #pragma unroll
            for (int nt = 0; nt < 10; ++nt)
                Psw[lr * PS_LD + nt * 16 + ml] = f2b(S[mt][nt][r]);
        }
        floatx4 O[4];
        #pragma unroll
        for (int j = 0; j < 4; ++j) O[j] = (floatx4){0.f, 0.f, 0.f, 0.f};
        #pragma unroll
        for (int ks = 0; ks < 5; ++ks) {
            short8 pf = *(const short8*)&Psw[ml * PS_LD + ks * 32 + quad * 8];
            #pragma unroll
            for (int nt = 0; nt < 4; ++nt) {
                short8 vf = *(const short8*)&Vt[(nt * 16 + ml) * VT_LD + ks * 32 + quad * 8];
                O[nt] = __builtin_amdgcn_mfma_f32_16x16x32_bf16(pf, vf, O[nt], 0, 0, 0);
            }
        }
        #pragma unroll
        for (int r = 0; r < 4; ++r) {
            int mm = wavebase + mt * 16 + quad * 4 + r;
            int tl = mm & 15, g = mm >> 4;
            unsigned short* op = aout + (size_t)(t0 + tl) * QCOLS + (kh * GQ + g) * DHEAD;
            #pragma unroll
            for (int nt = 0; nt < 4; ++nt)
                op[nt * 16 + ml] = f2b(O[nt][r]);
        }
    }
}

// ---------------------------------------------------------------------------
extern "C" void kernel_launch(void* const* d_in, const int* in_sizes, int n_in,
                              void* d_out, int out_size, void* d_ws, size_t ws_size,
                              hipStream_t stream) {
    const float* X     = (const float*)d_in[0];  // 1024x2880 f32
    const float* Wqkv  = (const float*)d_in[1];  // 2880x5120 f32
    const float* Wo    = (const float*)d_in[2];  // 4096x2880 f32
    const float* sinks = (const float*)d_in[3];  // 64 f32
    float* out = (float*)d_out;                  // 1024x2880 f32

    unsigned short *Xb, *qkvb, *attn, *WqkvT, *WoT;
    float *part1, *part2;
    hipGetSymbolAddress((void**)&Xb,    HIP_SYMBOL(g_Xb));
    hipGetSymbolAddress((void**)&qkvb,  HIP_SYMBOL(g_qkvb));
    hipGetSymbolAddress((void**)&attn,  HIP_SYMBOL(g_attn));
    hipGetSymbolAddress((void**)&WqkvT, HIP_SYMBOL(g_WqkvT));
    hipGetSymbolAddress((void**)&WoT,   HIP_SYMBOL(g_WoT));
    hipGetSymbolAddress((void**)&part1, HIP_SYMBOL(g_part1));
    hipGetSymbolAddress((void**)&part2, HIP_SYMBOL(g_part2));

    // Fused X-convert + both weight transposes (one launch)
    prep<<<T1_BLKS + T2_BLKS + CV_BLKS, 256, 0, stream>>>(X, Wqkv, Wo, Xb, WqkvT, WoT);

    // QKV projection, split-K=3, XCD-swizzled grid: 8 xcd * 5 grp * 24
    gemm_sk<<<8 * 5 * 8 * SK1, 256, 0, stream>>>(
        Xb, WqkvT, part1, HDIM, HDIM / SK1, QKV_N, (size_t)NTOK * QKV_N, SK1);

    // Reduce partials + RoPE -> bf16 qkv
    reduce_rope<<<(QK_UNITS + V_UNITS) / 256, 256, 0, stream>>>(part1, qkvb);

    // MFMA sliding-window attention -> bf16 attn
    attn_mfma<<<dim3(NTOK / TQ, NKV), 256, 0, stream>>>(qkvb, sinks, attn);

    // Output projection, split-K=4, XCD-swizzled grid: 8 xcd * 3 grp * 32
    gemm_sk<<<8 * 3 * 8 * SK2, 256, 0, stream>>>(
        attn, WoT, part2, QCOLS, QCOLS / SK2, WO_PAD, (size_t)NTOK * WO_PAD, SK2);

    // Reduce -> f32 out
    reduce_out<<<(NTOK * (HDIM / 4) + 255) / 256, 256, 0, stream>>>(part2, out);
}

// Round 9
// 335.296 us; speedup vs baseline: 1.0040x; 1.0040x over previous
//
#include <hip/hip_runtime.h>
#include <hip/hip_bf16.h>

// Problem constants
#define HDIM   2880
#define NH     64
#define NKV    8
#define DHEAD  64
#define GQ     (NH / NKV)     // 8
#define WIN    128
#define NTOK   1024
#define QKV_N  ((NH + 2 * NKV) * DHEAD)   // 5120
#define QCOLS  (NH * DHEAD)               // 4096
#define KOFF   QCOLS                      // 4096
#define VOFF   (QCOLS + NKV * DHEAD)      // 4608
#define WO_PAD 3072                       // 2880 padded to 24*128
#define SK1    5                          // split-K qkv gemm (2880 = 5*576)
#define SK2    8                          // split-K out gemm (4096 = 8*512)

typedef __attribute__((ext_vector_type(8))) short short8;
typedef __attribute__((ext_vector_type(4))) float floatx4;

// Static device scratch (zero-init at module load; WoT pad rows stay zero).
__device__ unsigned short g_Xb   [(size_t)NTOK  * HDIM];          //  5.9 MB
__device__ unsigned short g_qkvb [(size_t)NTOK  * QKV_N];         // 10.5 MB bf16 qkv (post-rope)
__device__ unsigned short g_attn [(size_t)NTOK  * QCOLS];         //  8.4 MB
__device__ unsigned short g_WqkvT[(size_t)QKV_N * HDIM];          // 29.5 MB
__device__ unsigned short g_WoT  [(size_t)WO_PAD * QCOLS];        // 25.2 MB (padded)
__device__ unsigned short g_part1[(size_t)SK1 * NTOK * QKV_N];    // 52.4 MB bf16 partials
__device__ unsigned short g_part2[(size_t)SK2 * NTOK * WO_PAD];   // 50.3 MB bf16 partials

__device__ __forceinline__ unsigned short f2b(float f) {
    __hip_bfloat16 h = __float2bfloat16(f);
    return *reinterpret_cast<unsigned short*>(&h);
}
__device__ __forceinline__ float b2f(unsigned short u) {
    union { unsigned int i; float f; } x; x.i = ((unsigned int)u) << 16; return x.f;
}

__device__ __forceinline__ void gload_lds16(const unsigned short* g, unsigned short* l) {
    __builtin_amdgcn_global_load_lds(
        (const __attribute__((address_space(1))) unsigned int*)g,
        (__attribute__((address_space(3))) unsigned int*)l, 16, 0, 0);
}

// ---------------------------------------------------------------------------
// Fused prep: Wqkv transpose+cvt | Wo transpose+cvt | X cvt, one launch.
// ---------------------------------------------------------------------------
#define T1_BLKS (45 * 80)   // Wqkv: K=2880 (45), N=5120 (80)
#define T2_BLKS (64 * 45)   // Wo:   K=4096 (64), N=2880 (45)
#define CV_BLKS 2880        // X: 1024*2880/4/256

__global__ __launch_bounds__(256) void prep(
        const float* __restrict__ X, const float* __restrict__ Wqkv,
        const float* __restrict__ Wo, unsigned short* __restrict__ Xb,
        unsigned short* __restrict__ WqkvT, unsigned short* __restrict__ WoT) {
    __shared__ __align__(16) unsigned short T[64 * 72];
    int b = blockIdx.x, t = threadIdx.x;
    const float* in;
    unsigned short* out;
    int K, N, bk, bn;
    if (b < T1_BLKS) {
        in = Wqkv; out = WqkvT; K = HDIM; N = QKV_N;
        bk = b % 45; bn = b / 45;
    } else if (b < T1_BLKS + T2_BLKS) {
        int b2 = b - T1_BLKS;
        in = Wo; out = WoT; K = QCOLS; N = HDIM;
        bk = b2 % 64; bn = b2 / 64;
    } else {
        int id = (b - T1_BLKS - T2_BLKS) * 256 + t;
        float4 v = *(const float4*)(X + (size_t)id * 4);
        ushort4 o;
        o.x = f2b(v.x); o.y = f2b(v.y); o.z = f2b(v.z); o.w = f2b(v.w);
        *(ushort4*)(Xb + (size_t)id * 4) = o;
        return;
    }
    #pragma unroll
    for (int i = 0; i < 4; ++i) {
        int c = i * 256 + t;          // float4 slots
        int r = c >> 4, cc = (c & 15) * 4;
        float4 v = *(const float4*)(in + (size_t)(bk * 64 + r) * N + bn * 64 + cc);
        T[r * 72 + cc + 0] = f2b(v.x);
        T[r * 72 + cc + 1] = f2b(v.y);
        T[r * 72 + cc + 2] = f2b(v.z);
        T[r * 72 + cc + 3] = f2b(v.w);
    }
    __syncthreads();
    #pragma unroll
    for (int i = 0; i < 2; ++i) {
        int c = i * 256 + t;
        int rn = c >> 3, kc = (c & 7) * 8;
        int4 vv;
        unsigned short* tp = (unsigned short*)&vv;
        #pragma unroll
        for (int j = 0; j < 8; ++j) tp[j] = T[(kc + j) * 72 + rn];
        *(int4*)(out + (size_t)(bn * 64 + rn) * K + bk * 64 + kc) = vv;
    }
}

// ---------------------------------------------------------------------------
// Split-K GEMM: P[z] (M x ldc bf16) = A(MxK bf16)[chunk z] * Bt(ldc x K)^T.
// 128x128 tile, BK=64, 4 waves (2x2), 4x4 MFMA tiles/wave, global_load_lds.
// 3D grid (bm, bn, z); partials bf16 (halves round-trip traffic vs f32).
// ---------------------------------------------------------------------------
__global__ __launch_bounds__(256) void gemm_sk(
        const unsigned short* __restrict__ A, const unsigned short* __restrict__ Bt,
        unsigned short* __restrict__ P, int K, int chunk, int ldc, size_t plane) {
    int bm = blockIdx.x, bn = blockIdx.y, z = blockIdx.z;
    int t = threadIdx.x, lane = t & 63, wid = t >> 6;
    int quad = lane >> 4, ml = lane & 15;
    int wm = wid >> 1, wn = wid & 1;
    __shared__ __align__(16) unsigned short As[128 * 64];
    __shared__ __align__(16) unsigned short Bs[128 * 64];
    floatx4 acc[4][4];
    #pragma unroll
    for (int i = 0; i < 4; ++i)
        #pragma unroll
        for (int j = 0; j < 4; ++j) acc[i][j] = (floatx4){0.f, 0.f, 0.f, 0.f};

    int srow = lane >> 3;            // 0..7 within an 8-row group
    int scol = (lane & 7) * 8;       // 0..56
    int base = z * chunk;
    const unsigned short* Ab = A  + (size_t)(bm * 128) * K + base;
    const unsigned short* Bb = Bt + (size_t)(bn * 128) * K + base;

    for (int k0 = 0; k0 < chunk; k0 += 64) {
        #pragma unroll
        for (int j = 0; j < 4; ++j) {
            int grp = wid * 4 + j;               // 0..15: 8-row group
            int r = grp * 8 + srow;              // 0..127
            gload_lds16(Ab + (size_t)r * K + k0 + scol, &As[grp * 512]);
            gload_lds16(Bb + (size_t)r * K + k0 + scol, &Bs[grp * 512]);
        }
        __syncthreads();
        #pragma unroll
        for (int kk = 0; kk < 64; kk += 32) {
            short8 af[4], bf[4];
            #pragma unroll
            for (int mt = 0; mt < 4; ++mt)
                af[mt] = *(const short8*)&As[(wm * 64 + mt * 16 + ml) * 64 + kk + quad * 8];
            #pragma unroll
            for (int nt = 0; nt < 4; ++nt)
                bf[nt] = *(const short8*)&Bs[(wn * 64 + nt * 16 + ml) * 64 + kk + quad * 8];
            #pragma unroll
            for (int mt = 0; mt < 4; ++mt)
                #pragma unroll
                for (int nt = 0; nt < 4; ++nt)
                    acc[mt][nt] = __builtin_amdgcn_mfma_f32_16x16x32_bf16(af[mt], bf[nt], acc[mt][nt], 0, 0, 0);
        }
        __syncthreads();
    }
    unsigned short* Cp = P + z * plane;
    #pragma unroll
    for (int mt = 0; mt < 4; ++mt)
        #pragma unroll
        for (int nt = 0; nt < 4; ++nt)
            #pragma unroll
            for (int r = 0; r < 4; ++r) {
                int row = bm * 128 + wm * 64 + mt * 16 + quad * 4 + r;
                int col = bn * 128 + wn * 64 + nt * 16 + ml;
                Cp[(size_t)row * ldc + col] = f2b(acc[mt][nt][r]);
            }
}

// ---------------------------------------------------------------------------
// Reduce SK1 bf16 qkv partials + RoPE -> bf16 qkv. positions == row index.
// q/k unit: (n, head hh<72, octet o<4) covering dims d=o*8..o*8+7 (and +32).
// v unit: (n, 8-dim slot s<64).
// ---------------------------------------------------------------------------
#define QK8_UNITS (NTOK * 72 * 4)   // 294912
#define V8_UNITS  (NTOK * 64)       // 65536
__global__ __launch_bounds__(256) void reduce_rope(
        const unsigned short* __restrict__ P, unsigned short* __restrict__ qkvb) {
    int id = blockIdx.x * 256 + threadIdx.x;
    const size_t plane = (size_t)NTOK * QKV_N;
    if (id < QK8_UNITS) {
        int n = id / 288;
        int rem = id - n * 288;
        int hh = rem >> 2, o = rem & 3;
        int c0 = (hh < NH) ? hh * 64 : KOFF + (hh - NH) * 64;
        size_t i1 = (size_t)n * QKV_N + c0 + o * 8;
        float x1[8], x2[8];
        #pragma unroll
        for (int j = 0; j < 8; ++j) { x1[j] = 0.f; x2[j] = 0.f; }
        #pragma unroll
        for (int zz = 0; zz < SK1; ++zz) {
            int4 a = *(const int4*)(P + zz * plane + i1);
            int4 b = *(const int4*)(P + zz * plane + i1 + 32);
            const unsigned short* ap = (const unsigned short*)&a;
            const unsigned short* bp = (const unsigned short*)&b;
            #pragma unroll
            for (int j = 0; j < 8; ++j) { x1[j] += b2f(ap[j]); x2[j] += b2f(bp[j]); }
        }
        union { int4 v; unsigned short u[8]; } o1, o2;
        #pragma unroll
        for (int j = 0; j < 8; ++j) {
            int d = o * 8 + j;
            float inv = expf(-(float)d * 0.3724497053f);   // theta^(-d/32)
            float ang = (float)n * inv;
            float s, c;
            sincosf(ang, &s, &c);
            o1.u[j] = f2b(x1[j] * c - x2[j] * s);
            o2.u[j] = f2b(x2[j] * c + x1[j] * s);
        }
        *(int4*)(qkvb + i1) = o1.v;
        *(int4*)(qkvb + i1 + 32) = o2.v;
    } else if (id < QK8_UNITS + V8_UNITS) {
        int vid = id - QK8_UNITS;
        int n = vid >> 6, s = vid & 63;
        size_t i1 = (size_t)n * QKV_N + VOFF + s * 8;
        float v[8];
        #pragma unroll
        for (int j = 0; j < 8; ++j) v[j] = 0.f;
        #pragma unroll
        for (int zz = 0; zz < SK1; ++zz) {
            int4 a = *(const int4*)(P + zz * plane + i1);
            const unsigned short* ap = (const unsigned short*)&a;
            #pragma unroll
            for (int j = 0; j < 8; ++j) v[j] += b2f(ap[j]);
        }
        union { int4 w; unsigned short u[8]; } ov;
        #pragma unroll
        for (int j = 0; j < 8; ++j) ov.u[j] = f2b(v[j]);
        *(int4*)(qkvb + i1) = ov.w;
    }
}

// ---------------------------------------------------------------------------
// Reduce SK2 bf16 out-proj partials (ldc WO_PAD) -> f32 out (ld HDIM).
// Unit = (n, 8-col group c8 < 360).
// ---------------------------------------------------------------------------
__global__ __launch_bounds__(256) void reduce_out(
        const unsigned short* __restrict__ P, float* __restrict__ out) {
    int id = blockIdx.x * 256 + threadIdx.x;
    if (id >= NTOK * 360) return;
    int n = id / 360;
    int c = (id - n * 360) * 8;
    const size_t plane = (size_t)NTOK * WO_PAD;
    size_t i = (size_t)n * WO_PAD + c;
    float s[8];
    #pragma unroll
    for (int j = 0; j < 8; ++j) s[j] = 0.f;
    #pragma unroll
    for (int zz = 0; zz < SK2; ++zz) {
        int4 a = *(const int4*)(P + zz * plane + i);
        const unsigned short* ap = (const unsigned short*)&a;
        #pragma unroll
        for (int j = 0; j < 8; ++j) s[j] += b2f(ap[j]);
    }
    float4 lo = {s[0], s[1], s[2], s[3]};
    float4 hi = {s[4], s[5], s[6], s[7]};
    *(float4*)(out + (size_t)n * HDIM + c)     = lo;
    *(float4*)(out + (size_t)n * HDIM + c + 4) = hi;
}

// ---------------------------------------------------------------------------
// MFMA flash-style sliding-window attention with sinks, bf16 in/out.
// Block = (16-token Q-tile, kv-head) -> grid 64x8 = 512 blocks (2/CU).
// Vt staging: lane->(w fast) conflict-free scatter.
// ---------------------------------------------------------------------------
#define TQ     16
#define WROWS  160
#define KS_LD  72
#define VT_LD  168
#define PS_LD  168

__global__ __launch_bounds__(256) void attn_mfma(
        const unsigned short* __restrict__ qkvb,
        const float* __restrict__ sinks,
        unsigned short* __restrict__ aout) {
    int t0 = blockIdx.x * TQ, kh = blockIdx.y;
    int t = threadIdx.x, lane = t & 63, wid = t >> 6;
    int quad = lane >> 4, ml = lane & 15;
    int wavebase = wid * 32;

    __shared__ __align__(16) unsigned short Ks[WROWS * KS_LD];    // 22.5 KB
    __shared__ __align__(16) unsigned short Vt[DHEAD * VT_LD];    // 21   KB
    __shared__ __align__(16) unsigned short Ps[4 * 16 * PS_LD];   // 21   KB
    unsigned short* Psw = &Ps[wid * 16 * PS_LD];

    // ---- stage K row-major (coalesced int4)
    #pragma unroll
    for (int i = 0; i < 5; ++i) {
        int c = i * 256 + t;              // 0..1279 int4 slots
        int w = c >> 3, d8 = (c & 7) * 8;
        int r = t0 - 127 + w;
        r = min(max(r, 0), NTOK - 1);
        *(int4*)&Ks[w * KS_LD + d8] =
            *(const int4*)(qkvb + (size_t)r * QKV_N + KOFF + kh * DHEAD + d8);
    }
    // ---- stage V transposed: w varies across lanes -> conflict-free scatter
    #pragma unroll
    for (int i = 0; i < 5; ++i) {
        int c = i * 256 + t;              // 0..1279
        int w = c % 160, d8 = (c / 160) * 8;
        int r = t0 - 127 + w;
        r = min(max(r, 0), NTOK - 1);
        int4 vv = *(const int4*)(qkvb + (size_t)r * QKV_N + VOFF + kh * DHEAD + d8);
        const unsigned short* vp = (const unsigned short*)&vv;
        #pragma unroll
        for (int j = 0; j < 8; ++j) Vt[(d8 + j) * VT_LD + w] = vp[j];
    }
    __syncthreads();

    // ---- Q A-fragments straight from global bf16
    short8 qf[2][2];
    #pragma unroll
    for (int mt = 0; mt < 2; ++mt) {
        int m = wavebase + mt * 16 + ml;
        int tl = m & 15, g = m >> 4;
        const unsigned short* qp = qkvb + (size_t)(t0 + tl) * QKV_N + (kh * GQ + g) * DHEAD;
        #pragma unroll
        for (int kk = 0; kk < 2; ++kk)
            qf[mt][kk] = *(const short8*)(qp + kk * 32 + quad * 8);
    }

    // ---- S = Q K^T  (this wave: 2 m-tiles x 10 n-tiles)
    floatx4 S[2][10];
    #pragma unroll
    for (int mt = 0; mt < 2; ++mt)
        #pragma unroll
        for (int nt = 0; nt < 10; ++nt) S[mt][nt] = (floatx4){0.f, 0.f, 0.f, 0.f};
    #pragma unroll
    for (int kk = 0; kk < 2; ++kk) {
        #pragma unroll
        for (int nt = 0; nt < 10; ++nt) {
            short8 kb = *(const short8*)&Ks[(nt * 16 + ml) * KS_LD + kk * 32 + quad * 8];
            #pragma unroll
            for (int mt = 0; mt < 2; ++mt)
                S[mt][nt] = __builtin_amdgcn_mfma_f32_16x16x32_bf16(qf[mt][kk], kb, S[mt][nt], 0, 0, 0);
        }
    }

    // ---- band mask + scale   (valid: w>=tl, w<=tl+127, w>=127-t0)
    int wmin0 = 127 - t0;
    #pragma unroll
    for (int mt = 0; mt < 2; ++mt) {
        #pragma unroll
        for (int r = 0; r < 4; ++r) {
            int tl = (wavebase + mt * 16 + quad * 4 + r) & 15;
            int wlo = tl > wmin0 ? tl : wmin0;
            int whi = tl + 127;
            #pragma unroll
            for (int nt = 0; nt < 10; ++nt) {
                int w = nt * 16 + ml;
                float s = S[mt][nt][r] * 0.125f;
                S[mt][nt][r] = (w >= wlo && w <= whi) ? s : -INFINITY;
            }
        }
    }

    // ---- softmax with sink (rows spread over 16 lanes of the quad)
    #pragma unroll
    for (int mt = 0; mt < 2; ++mt) {
        int g = (wavebase + mt * 16) >> 4;
        float sk = sinks[kh * GQ + g];
        #pragma unroll
        for (int r = 0; r < 4; ++r) {
            float rm = -INFINITY;
            #pragma unroll
            for (int nt = 0; nt < 10; ++nt) rm = fmaxf(rm, S[mt][nt][r]);
            #pragma unroll
            for (int off = 1; off < 16; off <<= 1) rm = fmaxf(rm, __shfl_xor(rm, off));
            rm = fmaxf(rm, sk);
            float sum = 0.f;
            #pragma unroll
            for (int nt = 0; nt < 10; ++nt) {
                float p = __expf(S[mt][nt][r] - rm);   // exp(-inf)=0 masks
                S[mt][nt][r] = p;
                sum += p;
            }
            #pragma unroll
            for (int off = 1; off < 16; off <<= 1) sum += __shfl_xor(sum, off);
            float inv = 1.f / (sum + __expf(sk - rm));
            #pragma unroll
            for (int nt = 0; nt < 10; ++nt) S[mt][nt][r] *= inv;
        }
    }

    // ---- PV one m-tile at a time through per-wave Ps (wave DS ops in-order)
    #pragma unroll
    for (int mt = 0; mt < 2; ++mt) {
        #pragma unroll
        for (int r = 0; r < 4; ++r) {
            int lr = quad * 4 + r;
            #pragma unroll
            for (int nt = 0; nt < 10; ++nt)
                Psw[lr * PS_LD + nt * 16 + ml] = f2b(S[mt][nt][r]);
        }
        floatx4 O[4];
        #pragma unroll
        for (int j = 0; j < 4; ++j) O[j] = (floatx4){0.f, 0.f, 0.f, 0.f};
        #pragma unroll
        for (int ks = 0; ks < 5; ++ks) {
            short8 pf = *(const short8*)&Psw[ml * PS_LD + ks * 32 + quad * 8];
            #pragma unroll
            for (int nt = 0; nt < 4; ++nt) {
                short8 vf = *(const short8*)&Vt[(nt * 16 + ml) * VT_LD + ks * 32 + quad * 8];
                O[nt] = __builtin_amdgcn_mfma_f32_16x16x32_bf16(pf, vf, O[nt], 0, 0, 0);
            }
        }
        #pragma unroll
        for (int r = 0; r < 4; ++r) {
            int mm = wavebase + mt * 16 + quad * 4 + r;
            int tl = mm & 15, g = mm >> 4;
            unsigned short* op = aout + (size_t)(t0 + tl) * QCOLS + (kh * GQ + g) * DHEAD;
            #pragma unroll
            for (int nt = 0; nt < 4; ++nt)
                op[nt * 16 + ml] = f2b(O[nt][r]);
        }
    }
}

// ---------------------------------------------------------------------------
extern "C" void kernel_launch(void* const* d_in, const int* in_sizes, int n_in,
                              void* d_out, int out_size, void* d_ws, size_t ws_size,
                              hipStream_t stream) {
    const float* X     = (const float*)d_in[0];  // 1024x2880 f32
    const float* Wqkv  = (const float*)d_in[1];  // 2880x5120 f32
    const float* Wo    = (const float*)d_in[2];  // 4096x2880 f32
    const float* sinks = (const float*)d_in[3];  // 64 f32
    float* out = (float*)d_out;                  // 1024x2880 f32

    unsigned short *Xb, *qkvb, *attn, *WqkvT, *WoT, *part1, *part2;
    hipGetSymbolAddress((void**)&Xb,    HIP_SYMBOL(g_Xb));
    hipGetSymbolAddress((void**)&qkvb,  HIP_SYMBOL(g_qkvb));
    hipGetSymbolAddress((void**)&attn,  HIP_SYMBOL(g_attn));
    hipGetSymbolAddress((void**)&WqkvT, HIP_SYMBOL(g_WqkvT));
    hipGetSymbolAddress((void**)&WoT,   HIP_SYMBOL(g_WoT));
    hipGetSymbolAddress((void**)&part1, HIP_SYMBOL(g_part1));
    hipGetSymbolAddress((void**)&part2, HIP_SYMBOL(g_part2));

    // Fused X-convert + both weight transposes (one launch)
    prep<<<T1_BLKS + T2_BLKS + CV_BLKS, 256, 0, stream>>>(X, Wqkv, Wo, Xb, WqkvT, WoT);

    // QKV projection, split-K=5 (chunk 576) -> bf16 partials; 1600 blocks
    gemm_sk<<<dim3(NTOK / 128, QKV_N / 128, SK1), 256, 0, stream>>>(
        Xb, WqkvT, part1, HDIM, HDIM / SK1, QKV_N, (size_t)NTOK * QKV_N);

    // Reduce partials + RoPE -> bf16 qkv
    reduce_rope<<<(QK8_UNITS + V8_UNITS) / 256, 256, 0, stream>>>(part1, qkvb);

    // MFMA sliding-window attention -> bf16 attn
    attn_mfma<<<dim3(NTOK / TQ, NKV), 256, 0, stream>>>(qkvb, sinks, attn);

    // Output projection, split-K=8 (chunk 512) -> bf16 partials; 1536 blocks
    gemm_sk<<<dim3(NTOK / 128, WO_PAD / 128, SK2), 256, 0, stream>>>(
        attn, WoT, part2, QCOLS, QCOLS / SK2, WO_PAD, (size_t)NTOK * WO_PAD);

    // Reduce -> f32 out
    reduce_out<<<(NTOK * 360 + 255) / 256, 256, 0, stream>>>(part2, out);
}